// Round 7
// baseline (418.009 us; speedup 1.0000x reference)
//
#include <hip/hip_runtime.h>
#include <hip/hip_bf16.h>

#define D_MODEL 512
#define HEADS   8
#define DK      64
#define D_FF    1024
#define SEQ     2048
#define BATCH   4
#define NTOK    (BATCH*SEQ)          // 8192 rows
#define NELEM   (NTOK*D_MODEL)       // 4,194,304

#define QSCALE  0.18033688011112042f // 0.125 * log2(e)
#define MFIX    40.0f                // fixed softmax shift (exact: exp2(s-C)/sum)

typedef __attribute__((ext_vector_type(8))) short bf8_t;   // 8 bf16 (4 VGPRs)
typedef __attribute__((ext_vector_type(4))) float f4_t;    // 4 fp32

#define GLD16(gp, lp) __builtin_amdgcn_global_load_lds( \
    (const __attribute__((address_space(1))) void*)(gp), \
    (__attribute__((address_space(3))) void*)(lp), 16, 0, 0)

__device__ __forceinline__ float ldf(const void* p, size_t i, int f32) {
    return f32 ? ((const float*)p)[i] : __bfloat162float(((const __hip_bfloat16*)p)[i]);
}
__device__ __forceinline__ short f2bf(float f) {
    union { __hip_bfloat16 h; short s; } u; u.h = __float2bfloat16(f); return u.s;
}
__device__ __forceinline__ float bf2f(short s) {
    return __uint_as_float(((unsigned)(unsigned short)s) << 16);
}
__device__ __forceinline__ unsigned fbits(float f) { return __float_as_uint(f); }

// ---------------- dtype detector (bf16 vs fp32 inputs) ----------------
__global__ void detect_k(const uint4* __restrict__ w, int* __restrict__ flags) {
    __shared__ int found;
    if (threadIdx.x == 0) found = 0;
    __syncthreads();
    int hit = 0;
    for (int i = threadIdx.x; i < 4096; i += 256) {
        uint4 u = w[i];
        if (((u.x & 0x7F80u) == 0x7F80u) || ((u.y & 0x7F80u) == 0x7F80u) ||
            ((u.z & 0x7F80u) == 0x7F80u) || ((u.w & 0x7F80u) == 0x7F80u)) hit = 1;
    }
    if (hit) atomicOr(&found, 1);
    __syncthreads();
    if (threadIdx.x == 0) flags[0] = found ? 1 : 0;
}

// ---------------- fused prep: enc cast | maskbits | W1T | W2T | LN1(+cast) ----------------
__device__ __forceinline__ void transpose_body(const void* src, __hip_bfloat16* dst,
                                               int K, int N, int bxi, int byi, int f32,
                                               __hip_bfloat16 (*t)[33]) {
    int bx = bxi * 32, by = byi * 32;
    int tx = threadIdx.x & 31, ty = threadIdx.x >> 5;
    #pragma unroll
    for (int j = 0; j < 32; j += 8)
        t[ty + j][tx] = __float2bfloat16(ldf(src, (size_t)(by + ty + j) * N + bx + tx, f32));
    __syncthreads();
    #pragma unroll
    for (int j = 0; j < 32; j += 8)
        dst[(size_t)(bx + ty + j) * K + by + tx] = t[tx][ty + j];
}

__device__ __forceinline__ void ln_body(const void* x, const void* g, const void* b,
                                        int row, int f32, float* xout, __hip_bfloat16* y,
                                        bool write_x) {
    int lane = threadIdx.x & 63;
    size_t base = (size_t)row * D_MODEL;
    float v[8];
    float s = 0.f;
    #pragma unroll
    for (int i = 0; i < 8; i++) { v[i] = (x == xout && !write_x) ? xout[base + lane + i*64]
                                                                 : ldf(x, base + lane + i*64, f32); s += v[i]; }
    #pragma unroll
    for (int off = 32; off; off >>= 1) s += __shfl_xor(s, off);
    float mu = s * (1.f / D_MODEL);
    float ss = 0.f;
    #pragma unroll
    for (int i = 0; i < 8; i++) { float d = v[i] - mu; ss += d * d; }
    #pragma unroll
    for (int off = 32; off; off >>= 1) ss += __shfl_xor(ss, off);
    float rstd = rsqrtf(ss * (1.f / D_MODEL) + 1e-5f);
    #pragma unroll
    for (int i = 0; i < 8; i++) {
        int c = lane + i*64;
        if (write_x) xout[base + c] = v[i];
        y[base + c] = __float2bfloat16((v[i] - mu) * rstd * ldf(g, c, f32) + ldf(b, c, f32));
    }
}

__global__ __launch_bounds__(256)
void prep_k(const void* __restrict__ x, const void* __restrict__ enc,
            const int* __restrict__ mask,
            const void* __restrict__ W1, const void* __restrict__ W2,
            const void* __restrict__ ln1g, const void* __restrict__ ln1b,
            const int* __restrict__ flagp,
            float* __restrict__ bufX, __hip_bfloat16* __restrict__ bufQ,
            __hip_bfloat16* __restrict__ bufE, unsigned* __restrict__ mb,
            __hip_bfloat16* __restrict__ W1T, __hip_bfloat16* __restrict__ W2T) {
    __shared__ __hip_bfloat16 t[32][33];
    int f32 = *flagp;
    int bid = blockIdx.x;
    if (bid < 16384) {                       // enc -> bf16
        int i = bid * 256 + threadIdx.x;
        bufE[i] = __float2bfloat16(ldf(enc, i, f32));
    } else if (bid < 18432) {                // mask -> bits
        int row  = (bid - 16384) * 4 + (threadIdx.x >> 6);
        int lane = threadIdx.x & 63;
        const int* mr = mask + (size_t)row * SEQ;
        for (int it = 0; it < SEQ/64; it++) {
            unsigned long long bal = __ballot(mr[it*64 + lane] != 0);
            if (lane == 0)  mb[(size_t)row*(SEQ/32) + it*2]     = (unsigned)bal;
            if (lane == 32) mb[(size_t)row*(SEQ/32) + it*2 + 1] = (unsigned)(bal >> 32);
        }
    } else if (bid < 18944) {                // W1T[N=1024][K=512]
        int lb = bid - 18432;
        transpose_body(W1, W1T, D_MODEL, D_FF, lb & 31, lb >> 5, f32, t);
    } else if (bid < 19456) {                // W2T[N=512][K=1024]
        int lb = bid - 18944;
        transpose_body(W2, W2T, D_FF, D_MODEL, lb & 15, lb >> 4, f32, t);
    } else {                                 // LN1 + input cast
        int row = (bid - 19456) * 4 + (threadIdx.x >> 6);
        ln_body(x, ln1g, ln1b, row, f32, bufX, bufQ, true);
    }
}

// ---------------- layernorm (fp32 in, bf16 out) ----------------
__global__ __launch_bounds__(256)
void layernorm_k(const float* __restrict__ x, const void* __restrict__ g,
                 const void* __restrict__ b, const int* __restrict__ flagp,
                 __hip_bfloat16* __restrict__ y) {
    int f32  = *flagp;
    int row  = blockIdx.x * 4 + (threadIdx.x >> 6);
    ln_body(x, g, b, row, f32, (float*)x, y, false);
}

__device__ __forceinline__ bf8_t prescale_q(bf8_t q) {
    bf8_t r;
    #pragma unroll
    for (int j = 0; j < 8; j++) r[j] = f2bf(bf2f(q[j]) * QSCALE);
    return r;
}

// ---------------- MFMA flash attention: K from global (L1/L2), 256-key phases ----------------
// Block: 128 q of one (b,h); 4 waves x 32 q (2 groups of 16).
// S^T = K·Q^T; K A-frags loaded straight from global (16 rows x 64B per inst).
// p = exp2(s - MFIX) (exact shift); l via ones-row MFMA. V transposed in LDS.
template<bool HAS_MASK>
__global__ __launch_bounds__(256, 2)
void attn_mfma_k(const __hip_bfloat16* __restrict__ Q, const __hip_bfloat16* __restrict__ K,
                 const __hip_bfloat16* __restrict__ V, const unsigned* __restrict__ mbits,
                 float* __restrict__ Xout) {
    int bid = blockIdx.x;
    int qt = bid & 15;
    int h  = (bid >> 4) & 7;
    int b  = bid >> 7;
    int q0 = qt * 128;
    int tid  = threadIdx.x;
    int w    = tid >> 6;
    int lane = tid & 63;
    int c    = lane & 15;
    int quad = lane >> 4;

    __shared__ __hip_bfloat16 VT[4][64 * 64];     // [dk][key] per tile, chunk XOR
    __shared__ __hip_bfloat16 Pb[4][2][16 * 64];  // per-wave per-group P^T, XOR by q&7

    // Q fragments (B-operand), prescaled
    bf8_t qf[2][2];
    #pragma unroll
    for (int g = 0; g < 2; g++) {
        const __hip_bfloat16* qrp = Q + ((size_t)(b*SEQ + q0 + 32*w + 16*g + c)) * D_MODEL + h*DK;
        qf[g][0] = prescale_q(*(const bf8_t*)(qrp + quad*8));
        qf[g][1] = prescale_q(*(const bf8_t*)(qrp + 32 + quad*8));
    }

    // V read byte offsets (within one VT tile)
    int vpo[4][2];
    #pragma unroll
    for (int t = 0; t < 4; t++)
        #pragma unroll
        for (int kh = 0; kh < 2; kh++) {
            int row = 16*t + c;
            vpo[t][kh] = (row*64 + (((4*kh + quad) ^ (row & 7) ^ ((row >> 3) & 7)) * 8)) * 2;
        }

    // VT staging: thread owns keys (key0,key0+1) x dk [d0,d0+8)
    int key0 = (tid >> 3) * 2, d0 = (tid & 7) * 8;
    int vtwo[8];
    #pragma unroll
    for (int j = 0; j < 8; j++) {
        int dk = d0 + j;
        int ch = (key0 >> 3) ^ (dk & 7) ^ ((dk >> 3) & 7);
        vtwo[j] = dk*128 + ch*16 + (key0 & 7)*2;
    }

    // P buffer byte offsets (per wave, per group)
    char* pbw[2] = { (char*)&Pb[w][0][0], (char*)&Pb[w][1][0] };
    int pwoff[4], proff[2];
    #pragma unroll
    for (int nt = 0; nt < 4; nt++)
        pwoff[nt] = c*128 + (((2*nt + (quad >> 1)) ^ (c & 7)) * 16) + (quad & 1)*8;
    #pragma unroll
    for (int kh = 0; kh < 2; kh++)
        proff[kh] = c*128 + (((4*kh + quad) ^ (c & 7)) * 16);

    const unsigned* mrp[2] = {nullptr, nullptr};
    if (HAS_MASK) {
        mrp[0] = mbits + (size_t)(b*SEQ + q0 + 32*w + c) * (SEQ/32);
        mrp[1] = mrp[0] + (size_t)16 * (SEQ/32);
    }
    int qsh = quad * 4;

    // ones A-frag (row 0 only) for l row-sum MFMA
    short onev = (c == 0) ? (short)0x3F80 : (short)0;
    bf8_t ones = {onev, onev, onev, onev, onev, onev, onev, onev};

    f4_t o[2][4];
    #pragma unroll
    for (int g = 0; g < 2; g++)
        #pragma unroll
        for (int mt = 0; mt < 4; mt++) o[g][mt] = (f4_t){0.f,0.f,0.f,0.f};
    f4_t l_acc[2] = {(f4_t){0.f,0.f,0.f,0.f}, (f4_t){0.f,0.f,0.f,0.f}};

    const size_t kvbase = (size_t)b * SEQ * D_MODEL + (size_t)h * DK;

    for (int ph = 0; ph < SEQ/256; ph++) {
        int kb0 = ph * 256;
        __syncthreads();   // previous phase's VT reads done
        // ---- stage 4 V^T tiles (global loads batched, then pair-packed b32 writes) ----
        bf8_t v0[4], v1[4];
        #pragma unroll
        for (int t = 0; t < 4; t++) {
            const __hip_bfloat16* Vg = V + kvbase + (size_t)(kb0 + t*64 + key0) * D_MODEL + d0;
            v0[t] = *(const bf8_t*)Vg;
            v1[t] = *(const bf8_t*)(Vg + D_MODEL);
        }
        #pragma unroll
        for (int t = 0; t < 4; t++) {
            const unsigned* v0u = (const unsigned*)&v0[t];
            const unsigned* v1u = (const unsigned*)&v1[t];
            char* vb = (char*)&VT[t][0];
            #pragma unroll
            for (int dw = 0; dw < 4; dw++) {
                *(unsigned*)(vb + vtwo[2*dw])     = __builtin_amdgcn_perm(v1u[dw], v0u[dw], 0x05040100u);
                *(unsigned*)(vb + vtwo[2*dw + 1]) = __builtin_amdgcn_perm(v1u[dw], v0u[dw], 0x07060302u);
            }
        }
        __syncthreads();   // VT visible

        // ---- compute 4 tiles; K straight from global (no barrier involvement) ----
        #pragma unroll
        for (int t = 0; t < 4; t++) {
            int kb = kb0 + t*64;
            const __hip_bfloat16* Kg = K + kvbase + (size_t)kb * D_MODEL;
            const char* vtb = (const char*)&VT[t][0];

            // S^T = K Q^T ; K A-frag: rows 16nt+c, k = 32kh + quad*8
            f4_t s[2][4];
            #pragma unroll
            for (int nt = 0; nt < 4; nt++) { s[0][nt] = (f4_t){0.f,0.f,0.f,0.f}; s[1][nt] = (f4_t){0.f,0.f,0.f,0.f}; }
            #pragma unroll
            for (int nt = 0; nt < 4; nt++) {
                const __hip_bfloat16* krow = Kg + (size_t)(16*nt + c) * D_MODEL + quad*8;
                #pragma unroll
                for (int kh = 0; kh < 2; kh++) {
                    bf8_t kf = *(const bf8_t*)(krow + kh*32);
                    s[0][nt] = __builtin_amdgcn_mfma_f32_16x16x32_bf16(kf, qf[0][kh], s[0][nt], 0, 0, 0);
                    s[1][nt] = __builtin_amdgcn_mfma_f32_16x16x32_bf16(kf, qf[1][kh], s[1][nt], 0, 0, 0);
                }
            }

            // fixed-max exp + mask + pack -> per-wave LDS
            #pragma unroll
            for (int g = 0; g < 2; g++) {
                unsigned wq0 = 0xffffffffu, wq1 = 0xffffffffu;
                if (HAS_MASK) {
                    uint2 mw = *(const uint2*)(mrp[g] + (kb >> 5));
                    wq0 = mw.x >> qsh; wq1 = mw.y >> qsh;
                }
                #pragma unroll
                for (int nt = 0; nt < 4; nt++) {
                    #pragma unroll
                    for (int r = 0; r < 4; r++) {
                        float p = exp2f(s[g][nt][r] - MFIX);
                        if (HAS_MASK) {
                            unsigned sel = (nt < 2) ? wq0 : wq1;
                            if (!((sel >> ((nt & 1)*16 + r)) & 1u)) p = 0.f;
                        }
                        s[g][nt][r] = p;
                    }
                    unsigned pk0 = __builtin_amdgcn_perm(fbits(s[g][nt][1]), fbits(s[g][nt][0]), 0x07060302u);
                    unsigned pk1 = __builtin_amdgcn_perm(fbits(s[g][nt][3]), fbits(s[g][nt][2]), 0x07060302u);
                    *(uint2*)(pbw[g] + pwoff[nt]) = make_uint2(pk0, pk1);
                }
            }

            // O^T += V^T P^T ; l += ones·P^T
            #pragma unroll
            for (int kh = 0; kh < 2; kh++) {
                bf8_t pfA = *(const bf8_t*)(pbw[0] + proff[kh]);
                bf8_t pfB = *(const bf8_t*)(pbw[1] + proff[kh]);
                l_acc[0] = __builtin_amdgcn_mfma_f32_16x16x32_bf16(ones, pfA, l_acc[0], 0, 0, 0);
                l_acc[1] = __builtin_amdgcn_mfma_f32_16x16x32_bf16(ones, pfB, l_acc[1], 0, 0, 0);
                #pragma unroll
                for (int mt = 0; mt < 4; mt++) {
                    bf8_t vf = *(const bf8_t*)(vtb + vpo[mt][kh]);
                    o[0][mt] = __builtin_amdgcn_mfma_f32_16x16x32_bf16(vf, pfA, o[0][mt], 0, 0, 0);
                    o[1][mt] = __builtin_amdgcn_mfma_f32_16x16x32_bf16(vf, pfB, o[1][mt], 0, 0, 0);
                }
            }
        }
    }

    // epilogue: l broadcast from (quad=0, lane=c) reg0; Xout += O/l
    #pragma unroll
    for (int g = 0; g < 2; g++) {
        float lq = __shfl(l_acc[g][0], c);
        float il = 1.f / fmaxf(lq, 1e-35f);
        size_t rb = ((size_t)(b*SEQ + q0 + 32*w + 16*g + c)) * D_MODEL + h*DK;
        #pragma unroll
        for (int mt = 0; mt < 4; mt++)
            #pragma unroll
            for (int r = 0; r < 4; r++)
                Xout[rb + 16*mt + quad*4 + r] += o[g][mt][r] * il;
    }
}

// ---------------- MFMA GEMM1: bufH = relu(A @ W1T^T + b1); 128x64 tiles, 1024 blocks ----------------
__global__ __launch_bounds__(256, 4)
void gemm_relu_k(const __hip_bfloat16* __restrict__ A, const __hip_bfloat16* __restrict__ BT,
                 const void* __restrict__ bias, const int* __restrict__ flagp,
                 __hip_bfloat16* __restrict__ C, int Ksz, int Nsz) {
    int f32 = *flagp;
    __shared__ __hip_bfloat16 As[128 * 64];
    __shared__ __hip_bfloat16 Bs[64 * 64];
    int tid  = threadIdx.x;
    int w    = tid >> 6;
    int c    = tid & 15;
    int quad = (tid >> 4) & 3;
    int r0 = blockIdx.y * 128, c0 = blockIdx.x * 64;

    f4_t acc[2][4];
    #pragma unroll
    for (int i = 0; i < 2; i++)
        #pragma unroll
        for (int j = 0; j < 4; j++) acc[i][j] = (f4_t){0.f,0.f,0.f,0.f};

    for (int k0 = 0; k0 < Ksz; k0 += 64) {
        __syncthreads();
        #pragma unroll
        for (int i = 0; i < 4; i++) {
            int idx = i*256 + tid;
            int row = idx >> 3, c8 = idx & 7;
            GLD16(A + (size_t)(r0 + row) * Ksz + k0 + ((c8 ^ (row & 7)) * 8),
                  (char*)As + (size_t)(i*256 + w*64) * 16);
        }
        #pragma unroll
        for (int i = 0; i < 2; i++) {
            int idx = i*256 + tid;
            int row = idx >> 3, c8 = idx & 7;
            GLD16(BT + (size_t)(c0 + row) * Ksz + k0 + ((c8 ^ (row & 7)) * 8),
                  (char*)Bs + (size_t)(i*256 + w*64) * 16);
        }
        __syncthreads();

        #pragma unroll
        for (int kh = 0; kh < 2; kh++) {
            bf8_t af[2], bf[4];
            #pragma unroll
            for (int mt = 0; mt < 2; mt++) {
                int row = w*32 + mt*16 + c;
                af[mt] = *(const bf8_t*)&As[row*64 + (((kh*4 + quad) ^ (row & 7)) * 8)];
            }
            #pragma unroll
            for (int nt = 0; nt < 4; nt++) {
                int row = nt*16 + c;
                bf[nt] = *(const bf8_t*)&Bs[row*64 + (((kh*4 + quad) ^ (row & 7)) * 8)];
            }
            #pragma unroll
            for (int mt = 0; mt < 2; mt++)
                #pragma unroll
                for (int nt = 0; nt < 4; nt++)
                    acc[mt][nt] = __builtin_amdgcn_mfma_f32_16x16x32_bf16(af[mt], bf[nt], acc[mt][nt], 0, 0, 0);
        }
    }

    #pragma unroll
    for (int mt = 0; mt < 2; mt++)
        #pragma unroll
        for (int nt = 0; nt < 4; nt++) {
            int col = c0 + nt*16 + c;
            float bv = ldf(bias, col, f32);
            #pragma unroll
            for (int r = 0; r < 4; r++) {
                int m = r0 + w*32 + mt*16 + quad*4 + r;
                C[(size_t)m * Nsz + col] = __float2bfloat16(fmaxf(acc[mt][nt][r] + bv, 0.f));
            }
        }
}

// ---------------- MFMA GEMM2: out = resid + A @ W2T^T + b2; 64x64 tiles, 1024 blocks ----------------
__global__ __launch_bounds__(256, 4)
void gemm_out_k(const __hip_bfloat16* __restrict__ A, const __hip_bfloat16* __restrict__ BT,
                const void* __restrict__ bias, const float* __restrict__ resid,
                const int* __restrict__ flagp, void* __restrict__ out, int Ksz, int Nsz) {
    int f32 = *flagp;
    __shared__ __hip_bfloat16 As[64 * 64];
    __shared__ __hip_bfloat16 Bs[64 * 64];
    int tid  = threadIdx.x;
    int w    = tid >> 6;
    int c    = tid & 15;
    int quad = (tid >> 4) & 3;
    int r0 = blockIdx.y * 64, c0 = blockIdx.x * 64;

    f4_t acc[4];
    #pragma unroll
    for (int j = 0; j < 4; j++) acc[j] = (f4_t){0.f,0.f,0.f,0.f};

    for (int k0 = 0; k0 < Ksz; k0 += 64) {
        __syncthreads();
        #pragma unroll
        for (int i = 0; i < 2; i++) {
            int idx = i*256 + tid;
            int row = idx >> 3, c8 = idx & 7;
            GLD16(A + (size_t)(r0 + row) * Ksz + k0 + ((c8 ^ (row & 7)) * 8),
                  (char*)As + (size_t)(i*256 + w*64) * 16);
            GLD16(BT + (size_t)(c0 + row) * Ksz + k0 + ((c8 ^ (row & 7)) * 8),
                  (char*)Bs + (size_t)(i*256 + w*64) * 16);
        }
        __syncthreads();

        #pragma unroll
        for (int kh = 0; kh < 2; kh++) {
            int arow = w*16 + c;
            bf8_t af = *(const bf8_t*)&As[arow*64 + (((kh*4 + quad) ^ (arow & 7)) * 8)];
            #pragma unroll
            for (int nt = 0; nt < 4; nt++) {
                int row = nt*16 + c;
                bf8_t bf = *(const bf8_t*)&Bs[row*64 + (((kh*4 + quad) ^ (row & 7)) * 8)];
                acc[nt] = __builtin_amdgcn_mfma_f32_16x16x32_bf16(af, bf, acc[nt], 0, 0, 0);
            }
        }
    }

    #pragma unroll
    for (int nt = 0; nt < 4; nt++) {
        int col = c0 + nt*16 + c;
        float bv = ldf(bias, col, f32);
        #pragma unroll
        for (int r = 0; r < 4; r++) {
            int m = r0 + w*16 + quad*4 + r;
            float v = acc[nt][r] + bv + resid[(size_t)m * Nsz + col];
            if (f32) ((float*)out)[(size_t)m * Nsz + col] = v;
            else     ((__hip_bfloat16*)out)[(size_t)m * Nsz + col] = __float2bfloat16(v);
        }
    }
}

// ---------------- launch ----------------
extern "C" void kernel_launch(void* const* d_in, const int* in_sizes, int n_in,
                              void* d_out, int out_size, void* d_ws, size_t ws_size,
                              hipStream_t stream) {
    const void* x    = d_in[0];
    const void* enc  = d_in[1];
    const int*  mask = (const int*)d_in[2];
    const void* ln1g = d_in[3];
    const void* ln1b = d_in[4];
    const void* ln2g = d_in[5];
    const void* ln2b = d_in[6];
    const void* ln3g = d_in[7];
    const void* ln3b = d_in[8];
    const void* W1   = d_in[9];
    const void* b1   = d_in[10];
    const void* W2   = d_in[11];
    const void* b2   = d_in[12];

    char* ws = (char*)d_ws;
    float*          bufX  = (float*)ws;                                // 16MB fp32 residual
    __hip_bfloat16* bufQ  = (__hip_bfloat16*)(ws + (16u<<20));         // 8MB LN out bf16
    __hip_bfloat16* bufE  = (__hip_bfloat16*)(ws + (24u<<20));         // 8MB encoder bf16
    __hip_bfloat16* bufH  = (__hip_bfloat16*)(ws + (32u<<20));         // 16MB FFN hidden bf16
    __hip_bfloat16* W1T   = (__hip_bfloat16*)(ws + (48u<<20));         // 1MB
    __hip_bfloat16* W2T   = (__hip_bfloat16*)(ws + (49u<<20));         // 1MB
    unsigned*       mbits = (unsigned*)(ws + (50u<<20));               // 2MB
    int*            flags = (int*)(ws + (52u<<20));

    dim3 blk(256);
    detect_k<<<1, blk, 0, stream>>>((const uint4*)x, flags);
    // prep: enc cast | maskbits | W1T | W2T | LN1(+input cast)
    prep_k<<<21504, blk, 0, stream>>>(x, enc, mask, W1, W2, ln1g, ln1b, flags,
                                      bufX, bufQ, bufE, mbits, W1T, W2T);

    // masked self-attention + residual
    attn_mfma_k<true><<<BATCH*HEADS*(SEQ/128), blk, 0, stream>>>(bufQ, bufQ, bufQ, mbits, bufX);
    // LN2 + cross-attention + residual
    layernorm_k<<<NTOK/4, blk, 0, stream>>>(bufX, ln2g, ln2b, flags, bufQ);
    attn_mfma_k<false><<<BATCH*HEADS*(SEQ/128), blk, 0, stream>>>(bufQ, bufE, bufE, nullptr, bufX);
    // LN3 + FFN + residual (+final cast fused into GEMM2)
    layernorm_k<<<NTOK/4, blk, 0, stream>>>(bufX, ln3g, ln3b, flags, bufQ);
    gemm_relu_k<<<dim3(D_FF/64, NTOK/128), blk, 0, stream>>>(bufQ, W1T, b1, flags, bufH, D_MODEL, D_FF);
    gemm_out_k<<<dim3(D_MODEL/64, NTOK/64), blk, 0, stream>>>(bufH, W2T, b2, bufX, flags, d_out, D_FF, D_MODEL);
}

// Round 8
// 404.030 us; speedup vs baseline: 1.0346x; 1.0346x over previous
//
#include <hip/hip_runtime.h>
#include <hip/hip_bf16.h>

#define D_MODEL 512
#define HEADS   8
#define DK      64
#define D_FF    1024
#define SEQ     2048
#define BATCH   4
#define NTOK    (BATCH*SEQ)          // 8192 rows
#define NELEM   (NTOK*D_MODEL)       // 4,194,304

#define QSCALE  0.18033688011112042f // 0.125 * log2(e)
#define MFIX    40.0f                // fixed softmax shift, folded into MFMA C-init

typedef __attribute__((ext_vector_type(8))) short bf8_t;   // 8 bf16 (4 VGPRs)
typedef __attribute__((ext_vector_type(4))) float f4_t;    // 4 fp32

#define GLD16(gp, lp) __builtin_amdgcn_global_load_lds( \
    (const __attribute__((address_space(1))) void*)(gp), \
    (__attribute__((address_space(3))) void*)(lp), 16, 0, 0)

__device__ __forceinline__ float ldf(const void* p, size_t i, int f32) {
    return f32 ? ((const float*)p)[i] : __bfloat162float(((const __hip_bfloat16*)p)[i]);
}
__device__ __forceinline__ short f2bf(float f) {
    union { __hip_bfloat16 h; short s; } u; u.h = __float2bfloat16(f); return u.s;
}
__device__ __forceinline__ float bf2f(short s) {
    return __uint_as_float(((unsigned)(unsigned short)s) << 16);
}
__device__ __forceinline__ unsigned fbits(float f) { return __float_as_uint(f); }

// ---------------- dtype detector (bf16 vs fp32 inputs) ----------------
__global__ void detect_k(const uint4* __restrict__ w, int* __restrict__ flags) {
    __shared__ int found;
    if (threadIdx.x == 0) found = 0;
    __syncthreads();
    int hit = 0;
    for (int i = threadIdx.x; i < 4096; i += 256) {
        uint4 u = w[i];
        if (((u.x & 0x7F80u) == 0x7F80u) || ((u.y & 0x7F80u) == 0x7F80u) ||
            ((u.z & 0x7F80u) == 0x7F80u) || ((u.w & 0x7F80u) == 0x7F80u)) hit = 1;
    }
    if (hit) atomicOr(&found, 1);
    __syncthreads();
    if (threadIdx.x == 0) flags[0] = found ? 1 : 0;
}

// ---------------- fused prep: enc cast | maskbits | W1T | W2T | LN1(+cast) ----------------
__device__ __forceinline__ void transpose_body(const void* src, __hip_bfloat16* dst,
                                               int K, int N, int bxi, int byi, int f32,
                                               __hip_bfloat16 (*t)[33]) {
    int bx = bxi * 32, by = byi * 32;
    int tx = threadIdx.x & 31, ty = threadIdx.x >> 5;
    #pragma unroll
    for (int j = 0; j < 32; j += 8)
        t[ty + j][tx] = __float2bfloat16(ldf(src, (size_t)(by + ty + j) * N + bx + tx, f32));
    __syncthreads();
    #pragma unroll
    for (int j = 0; j < 32; j += 8)
        dst[(size_t)(bx + ty + j) * K + by + tx] = t[tx][ty + j];
}

__device__ __forceinline__ void ln_body(const void* x, const void* g, const void* b,
                                        int row, int f32, float* xout, __hip_bfloat16* y,
                                        bool write_x) {
    int lane = threadIdx.x & 63;
    size_t base = (size_t)row * D_MODEL;
    float v[8];
    float s = 0.f;
    #pragma unroll
    for (int i = 0; i < 8; i++) { v[i] = (x == xout && !write_x) ? xout[base + lane + i*64]
                                                                 : ldf(x, base + lane + i*64, f32); s += v[i]; }
    #pragma unroll
    for (int off = 32; off; off >>= 1) s += __shfl_xor(s, off);
    float mu = s * (1.f / D_MODEL);
    float ss = 0.f;
    #pragma unroll
    for (int i = 0; i < 8; i++) { float d = v[i] - mu; ss += d * d; }
    #pragma unroll
    for (int off = 32; off; off >>= 1) ss += __shfl_xor(ss, off);
    float rstd = rsqrtf(ss * (1.f / D_MODEL) + 1e-5f);
    #pragma unroll
    for (int i = 0; i < 8; i++) {
        int c = lane + i*64;
        if (write_x) xout[base + c] = v[i];
        y[base + c] = __float2bfloat16((v[i] - mu) * rstd * ldf(g, c, f32) + ldf(b, c, f32));
    }
}

__global__ __launch_bounds__(256)
void prep_k(const void* __restrict__ x, const void* __restrict__ enc,
            const int* __restrict__ mask,
            const void* __restrict__ W1, const void* __restrict__ W2,
            const void* __restrict__ ln1g, const void* __restrict__ ln1b,
            const int* __restrict__ flagp,
            float* __restrict__ bufX, __hip_bfloat16* __restrict__ bufQ,
            __hip_bfloat16* __restrict__ bufE, unsigned* __restrict__ mb,
            __hip_bfloat16* __restrict__ W1T, __hip_bfloat16* __restrict__ W2T) {
    __shared__ __hip_bfloat16 t[32][33];
    int f32 = *flagp;
    int bid = blockIdx.x;
    if (bid < 2048) {                        // enc -> bf16, 8 elems/thread
        size_t v = (size_t)bid * 2048 + (size_t)threadIdx.x * 8;
        __hip_bfloat16 tmp[8];
        if (f32) {
            float4 a = *(const float4*)((const float*)enc + v);
            float4 bq = *(const float4*)((const float*)enc + v + 4);
            tmp[0] = __float2bfloat16(a.x);  tmp[1] = __float2bfloat16(a.y);
            tmp[2] = __float2bfloat16(a.z);  tmp[3] = __float2bfloat16(a.w);
            tmp[4] = __float2bfloat16(bq.x); tmp[5] = __float2bfloat16(bq.y);
            tmp[6] = __float2bfloat16(bq.z); tmp[7] = __float2bfloat16(bq.w);
            *(uint4*)&bufE[v] = *(uint4*)tmp;
        } else {
            *(uint4*)&bufE[v] = *(const uint4*)((const __hip_bfloat16*)enc + v);
        }
    } else if (bid < 4096) {                 // mask -> bits
        int row  = (bid - 2048) * 4 + (threadIdx.x >> 6);
        int lane = threadIdx.x & 63;
        const int* mr = mask + (size_t)row * SEQ;
        for (int it = 0; it < SEQ/64; it++) {
            unsigned long long bal = __ballot(mr[it*64 + lane] != 0);
            if (lane == 0)  mb[(size_t)row*(SEQ/32) + it*2]     = (unsigned)bal;
            if (lane == 32) mb[(size_t)row*(SEQ/32) + it*2 + 1] = (unsigned)(bal >> 32);
        }
    } else if (bid < 4608) {                 // W1T[N=1024][K=512]
        int lb = bid - 4096;
        transpose_body(W1, W1T, D_MODEL, D_FF, lb & 31, lb >> 5, f32, t);
    } else if (bid < 5120) {                 // W2T[N=512][K=1024]
        int lb = bid - 4608;
        transpose_body(W2, W2T, D_FF, D_MODEL, lb & 15, lb >> 4, f32, t);
    } else {                                 // LN1 + input cast
        int row = (bid - 5120) * 4 + (threadIdx.x >> 6);
        ln_body(x, ln1g, ln1b, row, f32, bufX, bufQ, true);
    }
}

// ---------------- layernorm (fp32 in, bf16 out) ----------------
__global__ __launch_bounds__(256)
void layernorm_k(const float* __restrict__ x, const void* __restrict__ g,
                 const void* __restrict__ b, const int* __restrict__ flagp,
                 __hip_bfloat16* __restrict__ y) {
    int f32  = *flagp;
    int row  = blockIdx.x * 4 + (threadIdx.x >> 6);
    ln_body(x, g, b, row, f32, (float*)x, y, false);
}

__device__ __forceinline__ bf8_t prescale_q(bf8_t q) {
    bf8_t r;
    #pragma unroll
    for (int j = 0; j < 8; j++) r[j] = f2bf(bf2f(q[j]) * QSCALE);
    return r;
}

// ---------------- MFMA flash attention: reg-prefetch pipeline, 1 barrier/128 keys ----------------
// Block: 128 q of one (b,h); 4 waves x 32 q (2 groups of 16). K-tiles of 64 keys.
// S^T = K·Q^T with K A-frags prefetched 1 tile ahead into VGPRs (no LDS for K).
// V reg-loaded 1 phase ahead; VT ping-pong in LDS. p = exp2(s) with C-init = -MFIX.
template<bool HAS_MASK>
__global__ __launch_bounds__(256, 2)
void attn_mfma_k(const __hip_bfloat16* __restrict__ Q, const __hip_bfloat16* __restrict__ K,
                 const __hip_bfloat16* __restrict__ V, const unsigned* __restrict__ mbits,
                 float* __restrict__ Xout) {
    int bid = blockIdx.x;
    int qt = bid & 15;
    int h  = (bid >> 4) & 7;
    int b  = bid >> 7;
    int q0 = qt * 128;
    int tid  = threadIdx.x;
    int w    = tid >> 6;
    int lane = tid & 63;
    int c    = lane & 15;
    int quad = lane >> 4;

    __shared__ __hip_bfloat16 VT[2][2][64 * 64];  // [buf][tile][dk][key], chunk XOR
    __shared__ __hip_bfloat16 Pb[4][2][16 * 64];  // per-wave per-group P^T, XOR by q&7

    // Q fragments (B-operand), prescaled
    bf8_t qf[2][2];
    #pragma unroll
    for (int g = 0; g < 2; g++) {
        const __hip_bfloat16* qrp = Q + ((size_t)(b*SEQ + q0 + 32*w + 16*g + c)) * D_MODEL + h*DK;
        qf[g][0] = prescale_q(*(const bf8_t*)(qrp + quad*8));
        qf[g][1] = prescale_q(*(const bf8_t*)(qrp + 32 + quad*8));
    }

    // V read byte offsets (within one VT tile)
    int vpo[4][2];
    #pragma unroll
    for (int t = 0; t < 4; t++)
        #pragma unroll
        for (int kh = 0; kh < 2; kh++) {
            int row = 16*t + c;
            vpo[t][kh] = (row*64 + (((4*kh + quad) ^ (row & 7) ^ ((row >> 3) & 7)) * 8)) * 2;
        }

    // VT staging: thread owns keys (key0,key0+1) x dk [d0,d0+8)
    int key0 = (tid >> 3) * 2, d0 = (tid & 7) * 8;
    int vtwo[8];
    #pragma unroll
    for (int j = 0; j < 8; j++) {
        int dk = d0 + j;
        int ch = (key0 >> 3) ^ (dk & 7) ^ ((dk >> 3) & 7);
        vtwo[j] = dk*128 + ch*16 + (key0 & 7)*2;
    }

    // P buffer byte offsets (per wave, per group)
    char* pbw[2] = { (char*)&Pb[w][0][0], (char*)&Pb[w][1][0] };
    int pwoff[4], proff[2];
    #pragma unroll
    for (int nt = 0; nt < 4; nt++)
        pwoff[nt] = c*128 + (((2*nt + (quad >> 1)) ^ (c & 7)) * 16) + (quad & 1)*8;
    #pragma unroll
    for (int kh = 0; kh < 2; kh++)
        proff[kh] = c*128 + (((4*kh + quad) ^ (c & 7)) * 16);

    const unsigned* mrp[2] = {nullptr, nullptr};
    if (HAS_MASK) {
        mrp[0] = mbits + (size_t)(b*SEQ + q0 + 32*w + c) * (SEQ/32);
        mrp[1] = mrp[0] + (size_t)16 * (SEQ/32);
    }
    int qsh = quad * 4;

    // ones A-frag (row 0 only) for l row-sum MFMA
    short onev = (c == 0) ? (short)0x3F80 : (short)0;
    bf8_t ones = {onev, onev, onev, onev, onev, onev, onev, onev};

    f4_t o[2][4];
    #pragma unroll
    for (int g = 0; g < 2; g++)
        #pragma unroll
        for (int mt = 0; mt < 4; mt++) o[g][mt] = (f4_t){0.f,0.f,0.f,0.f};
    f4_t l_acc[2] = {(f4_t){0.f,0.f,0.f,0.f}, (f4_t){0.f,0.f,0.f,0.f}};

    const size_t kvbase = (size_t)b * SEQ * D_MODEL + (size_t)h * DK;
    const __hip_bfloat16* Kbase = K + kvbase + (size_t)c * D_MODEL + quad*8;

    // --- prefetch helpers ---
    auto loadK = [&](int t, bf8_t* kr) {
        const __hip_bfloat16* Kg = Kbase + (size_t)(t*64) * D_MODEL;
        #pragma unroll
        for (int nt = 0; nt < 4; nt++) {
            kr[2*nt]   = *(const bf8_t*)(Kg + (size_t)(16*nt) * D_MODEL);
            kr[2*nt+1] = *(const bf8_t*)(Kg + (size_t)(16*nt) * D_MODEL + 32);
        }
    };
    auto loadV = [&](int ph, bf8_t* v0, bf8_t* v1) {
        #pragma unroll
        for (int t = 0; t < 2; t++) {
            const __hip_bfloat16* Vg = V + kvbase + (size_t)(ph*128 + t*64 + key0) * D_MODEL + d0;
            v0[t] = *(const bf8_t*)Vg;
            v1[t] = *(const bf8_t*)(Vg + D_MODEL);
        }
    };
    auto writeVT = [&](int buf, bf8_t* v0, bf8_t* v1) {
        #pragma unroll
        for (int t = 0; t < 2; t++) {
            const unsigned* v0u = (const unsigned*)&v0[t];
            const unsigned* v1u = (const unsigned*)&v1[t];
            char* vb = (char*)&VT[buf][t][0];
            #pragma unroll
            for (int dw = 0; dw < 4; dw++) {
                *(unsigned*)(vb + vtwo[2*dw])     = __builtin_amdgcn_perm(v1u[dw], v0u[dw], 0x05040100u);
                *(unsigned*)(vb + vtwo[2*dw + 1]) = __builtin_amdgcn_perm(v1u[dw], v0u[dw], 0x07060302u);
            }
        }
    };

    const int NPH = SEQ/128;       // 16 phases, 2 tiles each
    bf8_t kr[2][8];                // K frags: current+next tile
    bf8_t vr0[2], vr1[2];          // V regs for one phase

    loadK(0, kr[0]);
    loadV(0, vr0, vr1);
    writeVT(0, vr0, vr1);
    loadK(1, kr[1]);

    for (int ph = 0; ph < NPH; ph++) {
        int cur = ph & 1, nxt = cur ^ 1;
        __syncthreads();           // VT[cur] visible; prefetches from last phase complete
        bool more = (ph + 1) < NPH;
        if (more) loadV(ph + 1, vr0, vr1);   // async, lands during compute

        #pragma unroll
        for (int t = 0; t < 2; t++) {
            int kb = ph*128 + t*64;
            const char* vtb = (const char*)&VT[cur][t][0];

            // --- S^T = K Q^T, C-init = -MFIX ---
            f4_t s[2][4];
            #pragma unroll
            for (int nt = 0; nt < 4; nt++) {
                s[0][nt] = (f4_t){-MFIX,-MFIX,-MFIX,-MFIX};
                s[1][nt] = (f4_t){-MFIX,-MFIX,-MFIX,-MFIX};
            }
            #pragma unroll
            for (int nt = 0; nt < 4; nt++)
                #pragma unroll
                for (int kh = 0; kh < 2; kh++) {
                    bf8_t kf = kr[t][2*nt + kh];
                    s[0][nt] = __builtin_amdgcn_mfma_f32_16x16x32_bf16(kf, qf[0][kh], s[0][nt], 0, 0, 0);
                    s[1][nt] = __builtin_amdgcn_mfma_f32_16x16x32_bf16(kf, qf[1][kh], s[1][nt], 0, 0, 0);
                }

            // --- reissue K prefetch for tile 2 ahead (regs just consumed) ---
            int tn = 2*ph + t + 2;
            if (tn < 2*NPH) loadK(tn, kr[t]);

            // --- fixed-max exp + mask + pack -> per-wave LDS ---
            #pragma unroll
            for (int g = 0; g < 2; g++) {
                unsigned wq0 = 0xffffffffu, wq1 = 0xffffffffu;
                if (HAS_MASK) {
                    uint2 mw = *(const uint2*)(mrp[g] + (kb >> 5));
                    wq0 = mw.x >> qsh; wq1 = mw.y >> qsh;
                }
                #pragma unroll
                for (int nt = 0; nt < 4; nt++) {
                    #pragma unroll
                    for (int r = 0; r < 4; r++) {
                        float p = exp2f(s[g][nt][r]);
                        if (HAS_MASK) {
                            unsigned sel = (nt < 2) ? wq0 : wq1;
                            if (!((sel >> ((nt & 1)*16 + r)) & 1u)) p = 0.f;
                        }
                        s[g][nt][r] = p;
                    }
                    unsigned pk0 = __builtin_amdgcn_perm(fbits(s[g][nt][1]), fbits(s[g][nt][0]), 0x07060302u);
                    unsigned pk1 = __builtin_amdgcn_perm(fbits(s[g][nt][3]), fbits(s[g][nt][2]), 0x07060302u);
                    *(uint2*)(pbw[g] + pwoff[nt]) = make_uint2(pk0, pk1);
                }
            }

            // --- O^T += V^T P^T ; l += ones·P^T ---
            #pragma unroll
            for (int kh = 0; kh < 2; kh++) {
                bf8_t pfA = *(const bf8_t*)(pbw[0] + proff[kh]);
                bf8_t pfB = *(const bf8_t*)(pbw[1] + proff[kh]);
                l_acc[0] = __builtin_amdgcn_mfma_f32_16x16x32_bf16(ones, pfA, l_acc[0], 0, 0, 0);
                l_acc[1] = __builtin_amdgcn_mfma_f32_16x16x32_bf16(ones, pfB, l_acc[1], 0, 0, 0);
                #pragma unroll
                for (int mt = 0; mt < 4; mt++) {
                    bf8_t vf = *(const bf8_t*)(vtb + vpo[mt][kh]);
                    o[0][mt] = __builtin_amdgcn_mfma_f32_16x16x32_bf16(vf, pfA, o[0][mt], 0, 0, 0);
                    o[1][mt] = __builtin_amdgcn_mfma_f32_16x16x32_bf16(vf, pfB, o[1][mt], 0, 0, 0);
                }
            }
        }

        if (more) writeVT(nxt, vr0, vr1);   // ds_writes into the other buffer
    }

    // epilogue: l broadcast from (quad=0, lane=c) reg0; Xout += O/l
    #pragma unroll
    for (int g = 0; g < 2; g++) {
        float lq = __shfl(l_acc[g][0], c);
        float il = 1.f / fmaxf(lq, 1e-35f);
        size_t rb = ((size_t)(b*SEQ + q0 + 32*w + 16*g + c)) * D_MODEL + h*DK;
        #pragma unroll
        for (int mt = 0; mt < 4; mt++)
            #pragma unroll
            for (int r = 0; r < 4; r++)
                Xout[rb + 16*mt + quad*4 + r] += o[g][mt][r] * il;
    }
}

// ---------------- MFMA GEMM1: bufH = relu(A @ W1T^T + b1); 128x64 tiles ----------------
__global__ __launch_bounds__(256, 4)
void gemm_relu_k(const __hip_bfloat16* __restrict__ A, const __hip_bfloat16* __restrict__ BT,
                 const void* __restrict__ bias, const int* __restrict__ flagp,
                 __hip_bfloat16* __restrict__ C, int Ksz, int Nsz) {
    int f32 = *flagp;
    __shared__ __hip_bfloat16 As[128 * 64];
    __shared__ __hip_bfloat16 Bs[64 * 64];
    int tid  = threadIdx.x;
    int w    = tid >> 6;
    int c    = tid & 15;
    int quad = (tid >> 4) & 3;
    int r0 = blockIdx.y * 128, c0 = blockIdx.x * 64;

    f4_t acc[2][4];
    #pragma unroll
    for (int i = 0; i < 2; i++)
        #pragma unroll
        for (int j = 0; j < 4; j++) acc[i][j] = (f4_t){0.f,0.f,0.f,0.f};

    for (int k0 = 0; k0 < Ksz; k0 += 64) {
        __syncthreads();
        #pragma unroll
        for (int i = 0; i < 4; i++) {
            int idx = i*256 + tid;
            int row = idx >> 3, c8 = idx & 7;
            GLD16(A + (size_t)(r0 + row) * Ksz + k0 + ((c8 ^ (row & 7)) * 8),
                  (char*)As + (size_t)(i*256 + w*64) * 16);
        }
        #pragma unroll
        for (int i = 0; i < 2; i++) {
            int idx = i*256 + tid;
            int row = idx >> 3, c8 = idx & 7;
            GLD16(BT + (size_t)(c0 + row) * Ksz + k0 + ((c8 ^ (row & 7)) * 8),
                  (char*)Bs + (size_t)(i*256 + w*64) * 16);
        }
        __syncthreads();

        #pragma unroll
        for (int kh = 0; kh < 2; kh++) {
            bf8_t af[2], bf[4];
            #pragma unroll
            for (int mt = 0; mt < 2; mt++) {
                int row = w*32 + mt*16 + c;
                af[mt] = *(const bf8_t*)&As[row*64 + (((kh*4 + quad) ^ (row & 7)) * 8)];
            }
            #pragma unroll
            for (int nt = 0; nt < 4; nt++) {
                int row = nt*16 + c;
                bf[nt] = *(const bf8_t*)&Bs[row*64 + (((kh*4 + quad) ^ (row & 7)) * 8)];
            }
            #pragma unroll
            for (int mt = 0; mt < 2; mt++)
                #pragma unroll
                for (int nt = 0; nt < 4; nt++)
                    acc[mt][nt] = __builtin_amdgcn_mfma_f32_16x16x32_bf16(af[mt], bf[nt], acc[mt][nt], 0, 0, 0);
        }
    }

    #pragma unroll
    for (int mt = 0; mt < 2; mt++)
        #pragma unroll
        for (int nt = 0; nt < 4; nt++) {
            int col = c0 + nt*16 + c;
            float bv = ldf(bias, col, f32);
            #pragma unroll
            for (int r = 0; r < 4; r++) {
                int m = r0 + w*32 + mt*16 + quad*4 + r;
                C[(size_t)m * Nsz + col] = __float2bfloat16(fmaxf(acc[mt][nt][r] + bv, 0.f));
            }
        }
}

// ---------------- MFMA GEMM2: out = resid + A @ W2T^T + b2; 64x64 tiles ----------------
__global__ __launch_bounds__(256, 4)
void gemm_out_k(const __hip_bfloat16* __restrict__ A, const __hip_bfloat16* __restrict__ BT,
                const void* __restrict__ bias, const float* __restrict__ resid,
                const int* __restrict__ flagp, void* __restrict__ out, int Ksz, int Nsz) {
    int f32 = *flagp;
    __shared__ __hip_bfloat16 As[64 * 64];
    __shared__ __hip_bfloat16 Bs[64 * 64];
    int tid  = threadIdx.x;
    int w    = tid >> 6;
    int c    = tid & 15;
    int quad = (tid >> 4) & 3;
    int r0 = blockIdx.y * 64, c0 = blockIdx.x * 64;

    f4_t acc[4];
    #pragma unroll
    for (int j = 0; j < 4; j++) acc[j] = (f4_t){0.f,0.f,0.f,0.f};

    for (int k0 = 0; k0 < Ksz; k0 += 64) {
        __syncthreads();
        #pragma unroll
        for (int i = 0; i < 2; i++) {
            int idx = i*256 + tid;
            int row = idx >> 3, c8 = idx & 7;
            GLD16(A + (size_t)(r0 + row) * Ksz + k0 + ((c8 ^ (row & 7)) * 8),
                  (char*)As + (size_t)(i*256 + w*64) * 16);
            GLD16(BT + (size_t)(c0 + row) * Ksz + k0 + ((c8 ^ (row & 7)) * 8),
                  (char*)Bs + (size_t)(i*256 + w*64) * 16);
        }
        __syncthreads();

        #pragma unroll
        for (int kh = 0; kh < 2; kh++) {
            int arow = w*16 + c;
            bf8_t af = *(const bf8_t*)&As[arow*64 + (((kh*4 + quad) ^ (arow & 7)) * 8)];
            #pragma unroll
            for (int nt = 0; nt < 4; nt++) {
                int row = nt*16 + c;
                bf8_t bf = *(const bf8_t*)&Bs[row*64 + (((kh*4 + quad) ^ (row & 7)) * 8)];
                acc[nt] = __builtin_amdgcn_mfma_f32_16x16x32_bf16(af, bf, acc[nt], 0, 0, 0);
            }
        }
    }

    #pragma unroll
    for (int nt = 0; nt < 4; nt++) {
        int col = c0 + nt*16 + c;
        float bv = ldf(bias, col, f32);
        #pragma unroll
        for (int r = 0; r < 4; r++) {
            int m = r0 + w*16 + quad*4 + r;
            float v = acc[nt][r] + bv + resid[(size_t)m * Nsz + col];
            if (f32) ((float*)out)[(size_t)m * Nsz + col] = v;
            else     ((__hip_bfloat16*)out)[(size_t)m * Nsz + col] = __float2bfloat16(v);
        }
    }
}

// ---------------- launch ----------------
extern "C" void kernel_launch(void* const* d_in, const int* in_sizes, int n_in,
                              void* d_out, int out_size, void* d_ws, size_t ws_size,
                              hipStream_t stream) {
    const void* x    = d_in[0];
    const void* enc  = d_in[1];
    const int*  mask = (const int*)d_in[2];
    const void* ln1g = d_in[3];
    const void* ln1b = d_in[4];
    const void* ln2g = d_in[5];
    const void* ln2b = d_in[6];
    const void* ln3g = d_in[7];
    const void* ln3b = d_in[8];
    const void* W1   = d_in[9];
    const void* b1   = d_in[10];
    const void* W2   = d_in[11];
    const void* b2   = d_in[12];

    char* ws = (char*)d_ws;
    float*          bufX  = (float*)ws;                                // 16MB fp32 residual
    __hip_bfloat16* bufQ  = (__hip_bfloat16*)(ws + (16u<<20));         // 8MB LN out bf16
    __hip_bfloat16* bufE  = (__hip_bfloat16*)(ws + (24u<<20));         // 8MB encoder bf16
    __hip_bfloat16* bufH  = (__hip_bfloat16*)(ws + (32u<<20));         // 16MB FFN hidden bf16
    __hip_bfloat16* W1T   = (__hip_bfloat16*)(ws + (48u<<20));         // 1MB
    __hip_bfloat16* W2T   = (__hip_bfloat16*)(ws + (49u<<20));         // 1MB
    unsigned*       mbits = (unsigned*)(ws + (50u<<20));               // 2MB
    int*            flags = (int*)(ws + (52u<<20));

    dim3 blk(256);
    detect_k<<<1, blk, 0, stream>>>((const uint4*)x, flags);
    // prep: enc cast | maskbits | W1T | W2T | LN1(+input cast)
    prep_k<<<7168, blk, 0, stream>>>(x, enc, mask, W1, W2, ln1g, ln1b, flags,
                                     bufX, bufQ, bufE, mbits, W1T, W2T);

    // masked self-attention + residual
    attn_mfma_k<true><<<BATCH*HEADS*(SEQ/128), blk, 0, stream>>>(bufQ, bufQ, bufQ, mbits, bufX);
    // LN2 + cross-attention + residual
    layernorm_k<<<NTOK/4, blk, 0, stream>>>(bufX, ln2g, ln2b, flags, bufQ);
    attn_mfma_k<false><<<BATCH*HEADS*(SEQ/128), blk, 0, stream>>>(bufQ, bufE, bufE, nullptr, bufX);
    // LN3 + FFN + residual (+final cast fused into GEMM2)
    layernorm_k<<<NTOK/4, blk, 0, stream>>>(bufX, ln3g, ln3b, flags, bufQ);
    gemm_relu_k<<<dim3(D_FF/64, NTOK/128), blk, 0, stream>>>(bufQ, W1T, b1, flags, bufH, D_MODEL, D_FF);
    gemm_out_k<<<dim3(D_MODEL/64, NTOK/64), blk, 0, stream>>>(bufH, W2T, b2, bufX, flags, d_out, D_FF, D_MODEL);
}